// Round 5
// baseline (218.150 us; speedup 1.0000x reference)
//
#include <hip/hip_runtime.h>

// Problem constants (fixed by setup_inputs)
constexpr int B = 4;
constexpr int C = 64;    // input channels
constexpr int O = 64;    // output channels (main conv)
constexpr int OOFF = 18; // offset channels = 2*3*3
constexpr int H = 192;
constexpr int W = 192;

typedef __attribute__((ext_vector_type(8))) short short8;   // 8 bf16 = 4 VGPR
typedef __attribute__((ext_vector_type(4))) float float4v;  // MFMA acc
typedef __attribute__((ext_vector_type(2))) float f32x2;    // v_pk_fma_f32 pair
typedef __attribute__((ext_vector_type(2))) uint u32x2;
typedef __attribute__((ext_vector_type(2))) __bf16 bf16x2;

__device__ inline ushort f2bf(float f) { // RNE via HW __bf16 convert
  return __builtin_bit_cast(ushort, (__bf16)f);
}
__device__ inline uint pk2bf(float lo, float hi) { // pack 2 bf16 (RNE)
  bf16x2 v;
  v.x = (__bf16)lo;
  v.y = (__bf16)hi;
  return __builtin_bit_cast(uint, v);
}
__device__ inline f32x2 upk(uint u) { // unpack 2 bf16 -> 2 f32
  u32x2 t;
  t.x = u << 16;
  t.y = u & 0xffff0000u;
  return __builtin_bit_cast(f32x2, t);
}

// -------------------------------------------------------------------------
// Kernel PRE (fused): blocks [0,9216): transpose x fp32 NCHW -> xtb bf16
// channels-last. [9216,9360): w_conv -> wBf (PERMUTED n-map oc = nt+4*col).
// [9360,9432): w_off -> wOf (plain n-map, N padded 18->32).
// -------------------------------------------------------------------------
__global__ __launch_bounds__(256) void k_pre(const float* __restrict__ x,
                                             ushort* __restrict__ xtb,
                                             const float* __restrict__ w_conv,
                                             ushort* __restrict__ wBf,
                                             const float* __restrict__ w_off,
                                             ushort* __restrict__ wOf) {
  __shared__ float tile[64][17];
  const int bid = blockIdx.x;
  const int tid = threadIdx.x;
  if (bid < 9216) { // transpose
    const int w0 = (bid % 12) * 16;
    const int h = (bid / 12) % 192;
    const int b = bid / 2304;
    const int wl = tid & 15;
    const int c0 = tid >> 4;
#pragma unroll
    for (int r = 0; r < 4; ++r) {
      const int c = c0 + r * 16;
      tile[c][wl] = x[(((size_t)b * C + c) * H + h) * W + w0 + wl];
    }
    __syncthreads();
    const int c = tid & 63;
    const int qq = tid >> 6;
#pragma unroll
    for (int r = 0; r < 4; ++r) {
      const int wq = qq + r * 4;
      xtb[(((size_t)b * H + h) * W + w0 + wq) * C + c] = f2bf(tile[c][wq]);
    }
  } else if (bid < 9360) { // wBf: 36864 entries
    const int i = (bid - 9216) * 256 + tid;
    const int j = i & 7;
    const int lane = (i >> 3) & 63;
    const int nt = (i >> 9) & 3;
    const int kstep = (i >> 11) & 1;
    const int kk = i >> 12;
    const int n = nt + 4 * (lane & 15); // permuted
    const int c = kstep * 32 + ((lane >> 4) & 3) * 8 + j;
    wBf[i] = f2bf(w_conv[((size_t)n * C + c) * 9 + kk]);
  } else { // wOf: 18432 entries
    const int i = (bid - 9360) * 256 + tid;
    const int j = i & 7;
    const int lane = (i >> 3) & 63;
    const int nt = (i >> 9) & 1;
    const int ks = (i >> 10) & 1;
    const int kk = i >> 11;
    const int n = nt * 16 + (lane & 15);
    const int c = ks * 32 + ((lane >> 4) & 3) * 8 + j;
    wOf[i] = (n < OOFF) ? f2bf(w_off[((size_t)n * C + c) * 9 + kk]) : (ushort)0;
  }
}

// -------------------------------------------------------------------------
// Kernel FUSED v3: offset-conv + deformable conv, 1 WAVE PER BLOCK.
// Traffic analysis (round 4): kernel is per-CU L1-BW bound (1.87 GB total:
// gathers 679 MB + wBf 679 MB + wOf 340 MB + phase-1 A 170 MB); occupancy/
// pipelining invariant 77us. Fix: wave owns the FULL 8x8 tile (64 px) x
// 64 oc, so the per-kk B-fragment reads (8 KB) amortize over 4x the pixels:
// wBf 679->170 MB, wOf 340->85 MB (~40% of all L1 traffic removed).
// Per-pixel arithmetic and accumulation order bit-identical to round 4.
// kk loop NOT unrolled (I-cache); mt sub-tiles unrolled (static reg idx).
// grid: 2304 one-wave blocks (9 waves/CU, fully resident) + XCD swizzle.
// -------------------------------------------------------------------------
__global__ __launch_bounds__(64) void k_fused(
    const ushort* __restrict__ xtb, const ushort* __restrict__ wOf,
    const float* __restrict__ b_off, const ushort* __restrict__ wBf,
    const float* __restrict__ b_conv, ushort* __restrict__ yt) {
  __shared__ ushort sA[2][64][8];                // [ks][row][j] = 2 KB (one wave)
  __shared__ __align__(16) float offBuf[64][20]; // [px][oc(18,pad20)] = 5 KB

  const int bid = blockIdx.x;
  const int xcd = bid & 7;
  const int s0 = bid >> 3; // 0..287
  const int b = xcd >> 1;
  const int half = xcd & 1;
  const int th = s0 / 24; // 0..11
  const int tw = s0 % 24; // 0..23
  const int h0 = half * 96 + th * 8, w0 = tw * 8;

  const int lane = threadIdx.x; // one wave
  const int col = lane & 15, quad = lane >> 4;
  const int pq = lane >> 2, qtr = lane & 3; // gather: px-in-subtile, ch-quarter

  // ===================== Phase 1: offset conv (M=64, N=18, K=576) ===========
  {
    float4v oacc[4][2]; // [mt][nt]
#pragma unroll
    for (int mt = 0; mt < 4; ++mt)
#pragma unroll
      for (int nt = 0; nt < 2; ++nt) oacc[mt][nt] = (float4v){0.f, 0.f, 0.f, 0.f};

    short8 oafr[2][4][2]; // [pb][mt][ks] A fragments, double-buffered

    auto oload = [&](int kk, int pb) {
      const int ky = kk / 3, kx = kk % 3;
      const int ww = w0 + (col & 7) + kx - 1;
      const bool wok = (unsigned)ww < (unsigned)W;
      const int wwc = min(max(ww, 0), W - 1);
#pragma unroll
      for (int mt = 0; mt < 4; ++mt) {
        const int hh = h0 + 2 * mt + (col >> 3) + ky - 1;
        const bool ok = wok && ((unsigned)hh < (unsigned)H);
        const int hhc = min(max(hh, 0), H - 1);
        const ushort* pa = xtb + (((size_t)b * H + hhc) * W + wwc) * C + quad * 8;
#pragma unroll
        for (int ks = 0; ks < 2; ++ks) {
          short8 v = (short8)0;
          if (ok) v = *(const short8*)(pa + ks * 32);
          oafr[pb][mt][ks] = v;
        }
      }
    };

    oload(0, 0);
#pragma unroll 2 // pb = kk&1 stays compile-time (rule: no runtime reg-array idx)
    for (int kk = 0; kk < 9; ++kk) {
      const int pb = kk & 1;
      if (kk < 8) oload(kk + 1, pb ^ 1);
#pragma unroll
      for (int ks = 0; ks < 2; ++ks)
#pragma unroll
        for (int nt = 0; nt < 2; ++nt) {
          const short8 bw =
              *(const short8*)&wOf[((((size_t)kk * 2 + ks) * 2 + nt) * 64 + lane) * 8];
#pragma unroll
          for (int mt = 0; mt < 4; ++mt) // bw reused 4x -> wOf traffic /4
            oacc[mt][nt] =
                __builtin_amdgcn_mfma_f32_16x16x32_bf16(oafr[pb][mt][ks], bw, oacc[mt][nt], 0, 0, 0);
        }
    }

    // distribute offsets: D[m=quad*4+r][n=nt*16+col] -> offBuf[px][oc]
#pragma unroll
    for (int nt = 0; nt < 2; ++nt) {
      const int oc = nt * 16 + col;
      if (oc < OOFF) {
        const float bias = b_off[oc];
#pragma unroll
        for (int mt = 0; mt < 4; ++mt)
#pragma unroll
          for (int r = 0; r < 4; ++r)
            offBuf[mt * 16 + quad * 4 + r][oc] = oacc[mt][nt][r] + bias;
      }
    }
  } // intra-wave LDS exchange: no barrier needed (same-wave ds ordering)

  // ===================== Phase 2: deformable conv (M=64 x N=64) =============
  const ushort* xbase = xtb + (size_t)b * H * W * C;
  const uint qoff = (uint)qtr * 16u; // 16B slice within line 0 of the pixel

  uint offs[4];       // corner byte offsets for the NEXT gather (single slot)
  float4 awv;         // bilinear weights for the CURRENT blend (single slot)
  uint4 gA[4], gB[4]; // one sub-tile's gathers in flight (32 VGPR)
  short8 bb[2][4];    // [ks][nt] current kk's B fragments (32 VGPR)

  auto calc = [&](int kk, int pp) { // pp = pixel index 0..63 (static per site)
    const float2 ov = *(const float2*)&offBuf[pp][2 * kk];
    const int ky = kk / 3, kx = kk % 3;
    const float pyf = ov.x + (float)(h0 + (pp >> 3) + ky - 1);
    const float pxf = ov.y + (float)(w0 + (pp & 7) + kx - 1);
    const float fy0 = floorf(pyf), fx0 = floorf(pxf);
    const float wy = pyf - fy0, wx = pxf - fx0;
    const int iy0 = (int)fy0, ix0 = (int)fx0;
    const int iy1 = iy0 + 1, ix1 = ix0 + 1;
    const bool vy0 = (unsigned)iy0 < (unsigned)H;
    const bool vy1 = (unsigned)iy1 < (unsigned)H;
    const bool vx0 = (unsigned)ix0 < (unsigned)W;
    const bool vx1 = (unsigned)ix1 < (unsigned)W;
    awv.x = (vy0 && vx0) ? (1.f - wy) * (1.f - wx) : 0.f;
    awv.y = (vy0 && vx1) ? (1.f - wy) * wx : 0.f;
    awv.z = (vy1 && vx0) ? wy * (1.f - wx) : 0.f;
    awv.w = (vy1 && vx1) ? wy * wx : 0.f;
    const int cy0 = min(max(iy0, 0), H - 1), cy1 = min(max(iy1, 0), H - 1);
    const int cx0 = min(max(ix0, 0), W - 1), cx1 = min(max(ix1, 0), W - 1);
    offs[0] = (uint)((cy0 * W + cx0) * (C * 2)) + qoff;
    offs[1] = (uint)((cy0 * W + cx1) * (C * 2)) + qoff;
    offs[2] = (uint)((cy1 * W + cx0) * (C * 2)) + qoff;
    offs[3] = (uint)((cy1 * W + cx1) * (C * 2)) + qoff;
  };

  auto loadAB = [&]() {
#pragma unroll
    for (int c = 0; c < 4; ++c)
      gA[c] = *(const uint4*)((const char*)xbase + offs[c]); // line 0 (ch 8q..)
#pragma unroll
    for (int c = 0; c < 4; ++c)
      gB[c] = *(const uint4*)((const char*)xbase + offs[c] + 64u); // line 1
  };
  auto blend = [&](const uint4* g, uint* pk) {
    const f32x2 a00 = {awv.x, awv.x};
    const f32x2 a01 = {awv.y, awv.y};
    const f32x2 a10 = {awv.z, awv.z};
    const f32x2 a11 = {awv.w, awv.w};
#pragma unroll
    for (int i = 0; i < 4; ++i) {
      f32x2 sv = upk(g[0][i]) * a00 + upk(g[1][i]) * a01 + upk(g[2][i]) * a10 + upk(g[3][i]) * a11;
      pk[i] = pk2bf(sv.x, sv.y);
    }
  };

  float4v acc[4][4]; // [mt][nt] = 64 VGPR
#pragma unroll
  for (int mt = 0; mt < 4; ++mt)
#pragma unroll
    for (int nt = 0; nt < 4; ++nt) acc[mt][nt] = (float4v){0.f, 0.f, 0.f, 0.f};

  calc(0, 0 * 16 + pq);
  loadAB(); // (kk=0, mt=0) in flight
#pragma unroll 1 // keep body ~1 sub-kernel in I-cache; all reg-array idx static
  for (int kk = 0; kk < 9; ++kk) {
    // B fragments for this kk, shared by all 4 sub-tiles (the 4x amortization)
#pragma unroll
    for (int ks = 0; ks < 2; ++ks)
#pragma unroll
      for (int nt = 0; nt < 4; ++nt)
        bb[ks][nt] = *(const short8*)&wBf[((((size_t)kk * 2 + ks) * 4 + nt) * 64 + lane) * 8];

#pragma unroll
    for (int mt = 0; mt < 4; ++mt) {
      uint pkA[4];
      blend(gA, pkA); // waits this sub-tile's gathers (issued one step ago)
      *(uint4*)&sA[0][pq | (qtr << 4)][0] = *(const uint4*)pkA;
      uint pkB[4];
      blend(gB, pkB);
      *(uint4*)&sA[1][pq | (qtr << 4)][0] = *(const uint4*)pkB;

      // prefetch next (kk, mt) step; tail prefetch re-reads (8, 0) harmlessly
      {
        const int nmt = (mt + 1) & 3;
        const int nkk = (mt == 3) ? min(kk + 1, 8) : kk;
        calc(nkk, nmt * 16 + pq);
        loadAB();
      }

      // intra-wave exchange: writes above, reads below, same wave => ordered.
#pragma unroll
      for (int ks = 0; ks < 2; ++ks) {
        const short8 a = *(const short8*)&sA[ks][lane][0];
#pragma unroll
        for (int nt = 0; nt < 4; ++nt)
          acc[mt][nt] = __builtin_amdgcn_mfma_f32_16x16x32_bf16(a, bb[ks][nt], acc[mt][nt], 0, 0, 0);
      }
    }
  }

  // epilogue: yt[b][h][w][c] bf16, oc = nt + 4*(lane&15) (permuted)
  float bias[4];
#pragma unroll
  for (int nt = 0; nt < 4; ++nt) bias[nt] = b_conv[4 * col + nt];
#pragma unroll
  for (int mt = 0; mt < 4; ++mt)
#pragma unroll
    for (int r = 0; r < 4; ++r) {
      const int pp = mt * 16 + quad * 4 + r; // pixel index in 8x8 tile
      const int hrow = h0 + (pp >> 3), wcol = w0 + (pp & 7);
      uint2 u;
      u.x = pk2bf(acc[mt][0][r] + bias[0], acc[mt][1][r] + bias[1]);
      u.y = pk2bf(acc[mt][2][r] + bias[2], acc[mt][3][r] + bias[3]);
      *(uint2*)&yt[((size_t)(b * H + hrow) * W + wcol) * C + 4 * col] = u;
    }
}

// -------------------------------------------------------------------------
// Kernel 4 v3: main 3x3 conv via bf16 MFMA, LDS-free.
// Same amortization fix: wave = 4 rows x 16 cols (64 px) x 64 oc, so the
// per-kk wBf reads (8 KB) serve 64 px instead of 32 -> wBf traffic halves
// (340->170 MB) and grid drops to 576 blocks (2304 waves = 9/CU, resident
// in one round at ~3 waves/SIMD). B loaded inline per (kk,ks,nt), reused
// across 4 row-subtiles; A double-buffered across kk. Same accumulation
// order per output as round 2/4 -> bit-identical.
// -------------------------------------------------------------------------
__global__ __launch_bounds__(256) void k_conv_main_mfma(
    const ushort* __restrict__ yt, const ushort* __restrict__ wBf,
    const float* __restrict__ b_conv, float* __restrict__ out) {
  const int w0 = blockIdx.x * 16;
  const int b = blockIdx.z;
  const int tid = threadIdx.x;
  const int wave = tid >> 6, lane = tid & 63;
  const int col = lane & 15, quad = lane >> 4;
  const int h0 = blockIdx.y * 16 + wave * 4; // 4 output rows per wave

  float4v acc[4][4]; // [mt][nt] = 64 VGPR
#pragma unroll
  for (int mt = 0; mt < 4; ++mt)
#pragma unroll
    for (int nt = 0; nt < 4; ++nt) acc[mt][nt] = (float4v){0.f, 0.f, 0.f, 0.f};

  short8 afr[2][4][2]; // [pb][mt][ks] = 64 VGPR

  auto load = [&](int kk, int pb) {
    const int ky = kk / 3, kx = kk % 3;
    const int ww = w0 + col + kx - 1;
    const bool wok = (unsigned)ww < (unsigned)W;
    const int wwc = min(max(ww, 0), W - 1);
#pragma unroll
    for (int mt = 0; mt < 4; ++mt) {
      const int hh = h0 + mt + ky - 1;
      const bool ok = wok && ((unsigned)hh < (unsigned)H);
      const int hhc = min(max(hh, 0), H - 1);
      const ushort* pa = yt + (((size_t)b * H + hhc) * W + wwc) * C + quad * 8;
#pragma unroll
      for (int ks = 0; ks < 2; ++ks) {
        short8 v = (short8)0;
        if (ok) v = *(const short8*)(pa + ks * 32);
        afr[pb][mt][ks] = v;
      }
    }
  };

  load(0, 0);
#pragma unroll 2 // pb stays compile-time
  for (int kk = 0; kk < 9; ++kk) {
    const int pb = kk & 1;
    if (kk < 8) load(kk + 1, pb ^ 1);
#pragma unroll
    for (int ks = 0; ks < 2; ++ks)
#pragma unroll
      for (int nt = 0; nt < 4; ++nt) {
        const short8 bb = *(const short8*)&wBf[((((size_t)kk * 2 + ks) * 4 + nt) * 64 + lane) * 8];
#pragma unroll
        for (int mt = 0; mt < 4; ++mt) // bb reused 4x
          acc[mt][nt] =
              __builtin_amdgcn_mfma_f32_16x16x32_bf16(afr[pb][mt][ks], bb, acc[mt][nt], 0, 0, 0);
      }
  }

  float bias[4];
#pragma unroll
  for (int nt = 0; nt < 4; ++nt) bias[nt] = b_conv[4 * col + nt];
#pragma unroll
  for (int mt = 0; mt < 4; ++mt) {
    const int h = h0 + mt;
#pragma unroll
    for (int nt = 0; nt < 4; ++nt) {
      const int oc = 4 * col + nt; // permuted C/D col -> oc
      float4 v;
      v.x = acc[mt][nt][0] + bias[nt];
      v.y = acc[mt][nt][1] + bias[nt];
      v.z = acc[mt][nt][2] + bias[nt];
      v.w = acc[mt][nt][3] + bias[nt];
      *(float4*)&out[(((size_t)b * O + oc) * H + h) * W + w0 + quad * 4] = v;
    }
  }
}

// -------------------------------------------------------------------------
extern "C" void kernel_launch(void* const* d_in, const int* in_sizes, int n_in,
                              void* d_out, int out_size, void* d_ws, size_t ws_size,
                              hipStream_t stream) {
  const float* x = (const float*)d_in[0];
  const float* w_off = (const float*)d_in[1];
  const float* b_off = (const float*)d_in[2];
  const float* w_conv = (const float*)d_in[3];
  const float* b_conv = (const float*)d_in[4];
  float* out = (float*)d_out;

  ushort* xtb = (ushort*)d_ws;              // B*H*W*C bf16
  ushort* yt = xtb + (size_t)B * H * W * C; // B*H*W*C bf16
  ushort* wBf = yt + (size_t)B * H * W * C; // 36864 bf16
  ushort* wOf = wBf + 36864;                // 18432 bf16

  k_pre<<<dim3(9432), dim3(256), 0, stream>>>(x, xtb, w_conv, wBf, w_off, wOf);
  k_fused<<<dim3(2304), dim3(64), 0, stream>>>(xtb, wOf, b_off, wBf, b_conv, yt);
  k_conv_main_mfma<<<dim3(W / 16, H / 16, B), dim3(256), 0, stream>>>(yt, wBf, b_conv, out);
}

// Round 6
// 206.478 us; speedup vs baseline: 1.0565x; 1.0565x over previous
//
#include <hip/hip_runtime.h>

// Problem constants (fixed by setup_inputs)
constexpr int B = 4;
constexpr int C = 64;    // input channels
constexpr int O = 64;    // output channels (main conv)
constexpr int OOFF = 18; // offset channels = 2*3*3
constexpr int H = 192;
constexpr int W = 192;

typedef __attribute__((ext_vector_type(8))) short short8;   // 8 bf16 = 4 VGPR
typedef __attribute__((ext_vector_type(4))) float float4v;  // MFMA acc
typedef __attribute__((ext_vector_type(2))) float f32x2;    // v_pk_fma_f32 pair
typedef __attribute__((ext_vector_type(2))) uint u32x2;
typedef __attribute__((ext_vector_type(2))) __bf16 bf16x2;

__device__ inline ushort f2bf(float f) { // RNE via HW __bf16 convert
  return __builtin_bit_cast(ushort, (__bf16)f);
}
__device__ inline uint pk2bf(float lo, float hi) { // pack 2 bf16 (RNE)
  bf16x2 v;
  v.x = (__bf16)lo;
  v.y = (__bf16)hi;
  return __builtin_bit_cast(uint, v);
}
__device__ inline f32x2 upk(uint u) { // unpack 2 bf16 -> 2 f32
  u32x2 t;
  t.x = u << 16;
  t.y = u & 0xffff0000u;
  return __builtin_bit_cast(f32x2, t);
}

// -------------------------------------------------------------------------
// Kernel PRE (fused): blocks [0,9216): transpose x fp32 NCHW -> xtb bf16
// channels-last. [9216,9360): w_conv -> wBf (PERMUTED n-map oc = nt+4*col).
// [9360,9432): w_off -> wOf (plain n-map, N padded 18->32).
// -------------------------------------------------------------------------
__global__ __launch_bounds__(256) void k_pre(const float* __restrict__ x,
                                             ushort* __restrict__ xtb,
                                             const float* __restrict__ w_conv,
                                             ushort* __restrict__ wBf,
                                             const float* __restrict__ w_off,
                                             ushort* __restrict__ wOf) {
  __shared__ float tile[64][17];
  const int bid = blockIdx.x;
  const int tid = threadIdx.x;
  if (bid < 9216) { // transpose
    const int w0 = (bid % 12) * 16;
    const int h = (bid / 12) % 192;
    const int b = bid / 2304;
    const int wl = tid & 15;
    const int c0 = tid >> 4;
#pragma unroll
    for (int r = 0; r < 4; ++r) {
      const int c = c0 + r * 16;
      tile[c][wl] = x[(((size_t)b * C + c) * H + h) * W + w0 + wl];
    }
    __syncthreads();
    const int c = tid & 63;
    const int qq = tid >> 6;
#pragma unroll
    for (int r = 0; r < 4; ++r) {
      const int wq = qq + r * 4;
      xtb[(((size_t)b * H + h) * W + w0 + wq) * C + c] = f2bf(tile[c][wq]);
    }
  } else if (bid < 9360) { // wBf: 36864 entries
    const int i = (bid - 9216) * 256 + tid;
    const int j = i & 7;
    const int lane = (i >> 3) & 63;
    const int nt = (i >> 9) & 3;
    const int kstep = (i >> 11) & 1;
    const int kk = i >> 12;
    const int n = nt + 4 * (lane & 15); // permuted
    const int c = kstep * 32 + ((lane >> 4) & 3) * 8 + j;
    wBf[i] = f2bf(w_conv[((size_t)n * C + c) * 9 + kk]);
  } else { // wOf: 18432 entries
    const int i = (bid - 9360) * 256 + tid;
    const int j = i & 7;
    const int lane = (i >> 3) & 63;
    const int nt = (i >> 9) & 1;
    const int ks = (i >> 10) & 1;
    const int kk = i >> 11;
    const int n = nt * 16 + (lane & 15);
    const int c = ks * 32 + ((lane >> 4) & 3) * 8 + j;
    wOf[i] = (n < OOFF) ? f2bf(w_off[((size_t)n * C + c) * 9 + kk]) : (ushort)0;
  }
}

// -------------------------------------------------------------------------
// Kernel FUSED v4: offset-conv + deformable conv with LDS-STAGED GATHERS.
// Diagnosis (rounds 0-5): k_fused pinned at ~77-79us invariant to occupancy,
// VGPR, weight traffic, line-splitting => bound by the scattered gather path:
// per-tile gather working set ~15KB has ~16x reuse, but 9+ concurrent tiles
// thrash the 32KB L1 -> 679 MB of scattered 64B L2/L3 requests ~= 79us.
// Fix: 4-wave block per 8x8 tile stages the 20-row x 24-col neighborhood
// (rows [h0-6,h0+13], cols [w0-8,w0+15], clamped; covers |dy|<5,|dx|<7 ~4sig)
// into LDS ONCE (61 KB coalesced; 148 MB chip-wide vs 679 MB scattered).
// Rare out-of-halo samples (~0.02%) take the exact global fallback (LDS is a
// verbatim xtb copy -> bit-identical). 16B-slice XOR swizzle (key = col&7)
// on BOTH write and read kills the 128B-stride bank conflict (16-way -> ~2).
// One __syncthreads between staging and phase 2. Per-wave compute = verified
// round-4 code (M=16/wave, same accumulation order). LDS 74752 B -> 2 blk/CU.
// -------------------------------------------------------------------------
__global__ __launch_bounds__(256) void k_fused(
    const ushort* __restrict__ xtb, const ushort* __restrict__ wOf,
    const float* __restrict__ b_off, const ushort* __restrict__ wBf,
    const float* __restrict__ b_conv, ushort* __restrict__ yt) {
  // staged tile: 20 rows x 24 cols x 64ch bf16; ushort idx = r*1536 + c*64 + slice*8
  __shared__ __align__(16) ushort stg[20 * 24 * 64];  // 61440 B
  __shared__ ushort sA[4][2][64][8];                  // [wave][ks][row][j] = 8 KB
  __shared__ __align__(16) float offBuf[4][16][20];   // [wave][px][oc(18,pad20)] = 5 KB

  const int bid = blockIdx.x;
  const int xcd = bid & 7;
  const int s0 = bid >> 3; // 0..287
  const int b = xcd >> 1;
  const int half = xcd & 1;
  const int th = s0 / 24; // 0..11
  const int tw = s0 % 24; // 0..23
  const int h0 = half * 96 + th * 8, w0 = tw * 8;

  const int tid = threadIdx.x;
  const int wave = tid >> 6, lane = tid & 63;
  const int hb = h0 + wave * 2; // this wave's 2-row band
  const int col = lane & 15, quad = lane >> 4;
  const int p = lane >> 2, qtr = lane & 3; // gather: pixel 0..15, ch-quarter

  // ===================== Stage x-neighborhood into LDS ======================
  // 60 units = 20 rows x 3 chunks(8px); per unit: 64 lanes x 16B = 1KB.
  // lane l covers staged col c24 = c3*8 + (l>>3), logical slice j = l&7,
  // stored at physical slice j ^ (c24&7)  [= (l&7)^((l>>3)&7) since c3*8%8==0].
  for (int i = wave; i < 60; i += 4) {
    const int r = i / 3, c3 = i % 3;
    const int ry = min(max(h0 - 6 + r, 0), H - 1);
    const int cxs = w0 - 8 + c3 * 8 + (lane >> 3);
    const int cx = min(max(cxs, 0), W - 1);
    const uint4 v = *(const uint4*)(xtb + (((size_t)b * H + ry) * W + cx) * C + (lane & 7) * 8);
    const int dst = r * 1536 + (c3 * 8 + (lane >> 3)) * 64 + (((lane & 7) ^ ((lane >> 3) & 7)) * 8);
    *(uint4*)&stg[dst] = v;
  }

  // ===================== Phase 1: offset conv (per wave, M=16) ==============
  {
    float4v oacc[2];
#pragma unroll
    for (int nt = 0; nt < 2; ++nt) oacc[nt] = (float4v){0.f, 0.f, 0.f, 0.f};

    short8 oafr[2][2]; // [pb][ks] — A fragments double-buffered; weights inline

    auto oload = [&](int kk, int pb) {
      const int ky = kk / 3, kx = kk % 3;
      const int hh = hb + (col >> 3) + ky - 1;
      const int ww = w0 + (col & 7) + kx - 1;
      const bool ok = ((unsigned)hh < (unsigned)H) && ((unsigned)ww < (unsigned)W);
      const int hhc = min(max(hh, 0), H - 1);
      const int wwc = min(max(ww, 0), W - 1);
      const ushort* pa = xtb + (((size_t)b * H + hhc) * W + wwc) * C + quad * 8;
#pragma unroll
      for (int ks = 0; ks < 2; ++ks) {
        short8 v = (short8)0;
        if (ok) v = *(const short8*)(pa + ks * 32);
        oafr[pb][ks] = v;
      }
    };

    oload(0, 0);
#pragma unroll 2 // keeps pb = kk&1 compile-time
    for (int kk = 0; kk < 9; ++kk) {
      const int pb = kk & 1;
      if (kk < 8) oload(kk + 1, pb ^ 1);
#pragma unroll
      for (int ks = 0; ks < 2; ++ks)
#pragma unroll
        for (int nt = 0; nt < 2; ++nt) {
          const short8 bw =
              *(const short8*)&wOf[((((size_t)kk * 2 + ks) * 2 + nt) * 64 + lane) * 8];
          oacc[nt] = __builtin_amdgcn_mfma_f32_16x16x32_bf16(oafr[pb][ks], bw, oacc[nt], 0, 0, 0);
        }
    }

    // distribute offsets: D[m=quad*4+r][n=nt*16+col] -> offBuf[wave][m][oc]
#pragma unroll
    for (int nt = 0; nt < 2; ++nt) {
      const int oc = nt * 16 + col;
      if (oc < OOFF) {
        const float bias = b_off[oc];
#pragma unroll
        for (int r = 0; r < 4; ++r)
          offBuf[wave][quad * 4 + r][oc] = oacc[nt][r] + bias;
      }
    }
  }

  // staging (all waves) must be visible before any wave's phase-2 LDS gathers
  __syncthreads();

  // ===================== Phase 2: deformable conv =====================
  const ushort* xbase = xtb + (size_t)b * H * W * C; // fallback base
  const uint q16 = (uint)qtr * 16u;

  auto blend = [&](const uint4* g, const float4& aw, uint* pk) {
    const f32x2 a00 = {aw.x, aw.x};
    const f32x2 a01 = {aw.y, aw.y};
    const f32x2 a10 = {aw.z, aw.z};
    const f32x2 a11 = {aw.w, aw.w};
#pragma unroll
    for (int i = 0; i < 4; ++i) {
      f32x2 sv = upk(g[0][i]) * a00 + upk(g[1][i]) * a01 + upk(g[2][i]) * a10 + upk(g[3][i]) * a11;
      pk[i] = pk2bf(sv.x, sv.y);
    }
  };

  float4v acc[4];
#pragma unroll
  for (int nt = 0; nt < 4; ++nt) acc[nt] = (float4v){0.f, 0.f, 0.f, 0.f};

#pragma unroll 1 // keep I-cache small; all reg-array indices static
  for (int kk = 0; kk < 9; ++kk) {
    // B fragments for this kk (L1/L2-hot)
    short8 bb[2][4];
#pragma unroll
    for (int ks = 0; ks < 2; ++ks)
#pragma unroll
      for (int nt = 0; nt < 4; ++nt)
        bb[ks][nt] = *(const short8*)&wBf[((((size_t)kk * 2 + ks) * 4 + nt) * 64 + lane) * 8];

    const int ky = kk / 3, kx = kk % 3;

    // ---- calc sampling coords / weights (identical math to round 4) ----
    const float2 ov = *(const float2*)&offBuf[wave][p][2 * kk];
    const float pyf = ov.x + (float)(hb + (p >> 3) + ky - 1);
    const float pxf = ov.y + (float)(w0 + (p & 7) + kx - 1);
    const float fy0 = floorf(pyf), fx0 = floorf(pxf);
    const float wy = pyf - fy0, wx = pxf - fx0;
    const int iy0 = (int)fy0, ix0 = (int)fx0;
    const int iy1 = iy0 + 1, ix1 = ix0 + 1;
    const bool vy0 = (unsigned)iy0 < (unsigned)H;
    const bool vy1 = (unsigned)iy1 < (unsigned)H;
    const bool vx0 = (unsigned)ix0 < (unsigned)W;
    const bool vx1 = (unsigned)ix1 < (unsigned)W;
    float4 awv;
    awv.x = (vy0 && vx0) ? (1.f - wy) * (1.f - wx) : 0.f;
    awv.y = (vy0 && vx1) ? (1.f - wy) * wx : 0.f;
    awv.z = (vy1 && vx0) ? wy * (1.f - wx) : 0.f;
    awv.w = (vy1 && vx1) ? wy * wx : 0.f;
    const int cy0 = min(max(iy0, 0), H - 1), cy1 = min(max(iy1, 0), H - 1);
    const int cx0 = min(max(ix0, 0), W - 1), cx1 = min(max(ix1, 0), W - 1);

    // ---- gather: LDS fast path (staged halo) or exact global fallback ----
    uint4 gA[4], gB[4];
    const int sy0 = cy0 - h0 + 6, sy1 = cy1 - h0 + 6;   // staged row slots
    const int sx0 = cx0 - w0 + 8, sx1 = cx1 - w0 + 8;   // staged col slots
    if (((unsigned)sy0 <= 19u) & ((unsigned)sy1 <= 19u) & ((unsigned)sx0 <= 23u) &
        ((unsigned)sx1 <= 23u)) {
      const int cA0 = sx0 * 64 + ((qtr ^ (sx0 & 7)) * 8);
      const int cA1 = sx1 * 64 + ((qtr ^ (sx1 & 7)) * 8);
      const int r0 = sy0 * 1536, r1 = sy1 * 1536;
      const int a00 = r0 + cA0, a01 = r0 + cA1, a10 = r1 + cA0, a11 = r1 + cA1;
      gA[0] = *(const uint4*)&stg[a00];
      gB[0] = *(const uint4*)&stg[a00 ^ 32]; // slice^4 => chunk B (bytes +64)
      gA[1] = *(const uint4*)&stg[a01];
      gB[1] = *(const uint4*)&stg[a01 ^ 32];
      gA[2] = *(const uint4*)&stg[a10];
      gB[2] = *(const uint4*)&stg[a10 ^ 32];
      gA[3] = *(const uint4*)&stg[a11];
      gB[3] = *(const uint4*)&stg[a11 ^ 32];
    } else {
      const char* xb = (const char*)xbase;
      const uint o00 = (uint)((cy0 * W + cx0) * (C * 2)) + q16;
      const uint o01 = (uint)((cy0 * W + cx1) * (C * 2)) + q16;
      const uint o10 = (uint)((cy1 * W + cx0) * (C * 2)) + q16;
      const uint o11 = (uint)((cy1 * W + cx1) * (C * 2)) + q16;
      gA[0] = *(const uint4*)(xb + o00);
      gB[0] = *(const uint4*)(xb + o00 + 64u);
      gA[1] = *(const uint4*)(xb + o01);
      gB[1] = *(const uint4*)(xb + o01 + 64u);
      gA[2] = *(const uint4*)(xb + o10);
      gB[2] = *(const uint4*)(xb + o10 + 64u);
      gA[3] = *(const uint4*)(xb + o11);
      gB[3] = *(const uint4*)(xb + o11 + 64u);
    }

    uint pkA[4];
    blend(gA, awv, pkA);
    *(uint4*)&sA[wave][0][p | (qtr << 4)][0] = *(const uint4*)pkA;
    uint pkB[4];
    blend(gB, awv, pkB);
    *(uint4*)&sA[wave][1][p | (qtr << 4)][0] = *(const uint4*)pkB;

    // intra-wave exchange: writes above, reads below, same wave => ordered.
#pragma unroll
    for (int ks = 0; ks < 2; ++ks) {
      const short8 a = *(const short8*)&sA[wave][ks][lane][0];
#pragma unroll
      for (int nt = 0; nt < 4; ++nt)
        acc[nt] = __builtin_amdgcn_mfma_f32_16x16x32_bf16(a, bb[ks][nt], acc[nt], 0, 0, 0);
    }
  }

  // epilogue: yt[b][h][w][c] bf16, oc = nt + 4*(lane&15) (permuted)
  float bias[4];
#pragma unroll
  for (int nt = 0; nt < 4; ++nt) bias[nt] = b_conv[4 * col + nt];
#pragma unroll
  for (int r = 0; r < 4; ++r) {
    const int pp = quad * 4 + r; // pixel index in this wave's 2x8 band
    const int hrow = hb + (pp >> 3), wcol = w0 + (pp & 7);
    uint2 u;
    u.x = pk2bf(acc[0][r] + bias[0], acc[1][r] + bias[1]);
    u.y = pk2bf(acc[2][r] + bias[2], acc[3][r] + bias[3]);
    *(uint2*)&yt[((size_t)(b * H + hrow) * W + wcol) * C + 4 * col] = u;
  }
}

// -------------------------------------------------------------------------
// Kernel 4: main 3x3 conv via bf16 MFMA, LDS-free, 1-stage pipelined frags.
// Round-2 known-good shape: 256 threads, wave = 2 rows x 64 oc (B-frags
// register-double-buffered, amortized over 2 rows). grid (12, 24, 4).
// -------------------------------------------------------------------------
__global__ __launch_bounds__(256) void k_conv_main_mfma(
    const ushort* __restrict__ yt, const ushort* __restrict__ wBf,
    const float* __restrict__ b_conv, float* __restrict__ out) {
  const int w0 = blockIdx.x * 16;
  const int b = blockIdx.z;
  const int tid = threadIdx.x;
  const int wave = tid >> 6, lane = tid & 63;
  const int col = lane & 15, quad = lane >> 4;
  const int h0 = blockIdx.y * 8 + wave * 2;

  float4v acc[2][4];
#pragma unroll
  for (int mt = 0; mt < 2; ++mt)
#pragma unroll
    for (int nt = 0; nt < 4; ++nt) acc[mt][nt] = (float4v){0.f, 0.f, 0.f, 0.f};

  short8 bfr[2][2][4]; // [pb][ks][nt]
  short8 afr[2][2][2]; // [pb][mt][ks]

  auto load = [&](int kk, int pb) {
    const int ky = kk / 3, kx = kk % 3;
    const int ww = w0 + col + kx - 1;
    const bool wok = (unsigned)ww < (unsigned)W;
    const int wwc = min(max(ww, 0), W - 1);
#pragma unroll
    for (int ks = 0; ks < 2; ++ks)
#pragma unroll
      for (int nt = 0; nt < 4; ++nt)
        bfr[pb][ks][nt] = *(const short8*)&wBf[((((size_t)kk * 2 + ks) * 4 + nt) * 64 + lane) * 8];
#pragma unroll
    for (int mt = 0; mt < 2; ++mt) {
      const int hh = h0 + mt + ky - 1;
      const bool ok = wok && ((unsigned)hh < (unsigned)H);
      const int hhc = min(max(hh, 0), H - 1);
      const ushort* pa = yt + (((size_t)b * H + hhc) * W + wwc) * C + quad * 8;
#pragma unroll
      for (int ks = 0; ks < 2; ++ks) {
        short8 v = (short8)0;
        if (ok) v = *(const short8*)(pa + ks * 32);
        afr[pb][mt][ks] = v;
      }
    }
  };

  load(0, 0);
#pragma unroll
  for (int kk = 0; kk < 9; ++kk) {
    const int pb = kk & 1;
    if (kk < 8) load(kk + 1, pb ^ 1);
#pragma unroll
    for (int ks = 0; ks < 2; ++ks)
#pragma unroll
      for (int mt = 0; mt < 2; ++mt)
#pragma unroll
        for (int nt = 0; nt < 4; ++nt)
          acc[mt][nt] = __builtin_amdgcn_mfma_f32_16x16x32_bf16(afr[pb][mt][ks], bfr[pb][ks][nt],
                                                                acc[mt][nt], 0, 0, 0);
  }

  float bias[4];
#pragma unroll
  for (int nt = 0; nt < 4; ++nt) bias[nt] = b_conv[4 * col + nt];
#pragma unroll
  for (int mt = 0; mt < 2; ++mt) {
    const int h = h0 + mt;
#pragma unroll
    for (int nt = 0; nt < 4; ++nt) {
      const int oc = 4 * col + nt; // permuted C/D col -> oc
      float4 v;
      v.x = acc[mt][nt][0] + bias[nt];
      v.y = acc[mt][nt][1] + bias[nt];
      v.z = acc[mt][nt][2] + bias[nt];
      v.w = acc[mt][nt][3] + bias[nt];
      *(float4*)&out[(((size_t)b * O + oc) * H + h) * W + w0 + quad * 4] = v;
    }
  }
}

// -------------------------------------------------------------------------
extern "C" void kernel_launch(void* const* d_in, const int* in_sizes, int n_in,
                              void* d_out, int out_size, void* d_ws, size_t ws_size,
                              hipStream_t stream) {
  const float* x = (const float*)d_in[0];
  const float* w_off = (const float*)d_in[1];
  const float* b_off = (const float*)d_in[2];
  const float* w_conv = (const float*)d_in[3];
  const float* b_conv = (const float*)d_in[4];
  float* out = (float*)d_out;

  ushort* xtb = (ushort*)d_ws;              // B*H*W*C bf16
  ushort* yt = xtb + (size_t)B * H * W * C; // B*H*W*C bf16
  ushort* wBf = yt + (size_t)B * H * W * C; // 36864 bf16
  ushort* wOf = wBf + 36864;                // 18432 bf16

  k_pre<<<dim3(9432), dim3(256), 0, stream>>>(x, xtb, w_conv, wBf, w_off, wOf);
  k_fused<<<dim3(2304), dim3(256), 0, stream>>>(xtb, wOf, b_off, wBf, b_conv, yt);
  k_conv_main_mfma<<<dim3(W / 16, H / 8, B), dim3(256), 0, stream>>>(yt, wBf, b_conv, out);
}